// Round 6
// baseline (1726.991 us; speedup 1.0000x reference)
//
#include <hip/hip_runtime.h>
#include <hip/hip_bf16.h>
#include <stdint.h>

#define B_SZ 256
#define H_SZ 1024
#define NG   4096   // 4*H
#define F_SZ 32
#define T_SZ 96

typedef __attribute__((ext_vector_type(8))) short short8;
typedef __attribute__((ext_vector_type(4))) float f32x4;

__device__ __forceinline__ unsigned short f2bf(float x) {
  unsigned int u = __float_as_uint(x);
  u += 0x7fffu + ((u >> 16) & 1u);   // RNE
  return (unsigned short)(u >> 16);
}
__device__ __forceinline__ float sigf(float x) {
  return 1.f / (1.f + __expf(-x));
}
__device__ __forceinline__ float tanh_fast(float x) {
  float e = __expf(-2.f * fabsf(x));
  float t = (1.f - e) / (1.f + e);
  return copysignf(t, x);
}
__device__ __forceinline__ void stage16(const void* g, void* l) {
  __builtin_amdgcn_global_load_lds(
      (const __attribute__((address_space(1))) void*)g,
      (__attribute__((address_space(3))) void*)l, 16, 0, 0);
}

// ---------------------------------------------------------------------------
// Prep: WeffT[n][k] = (W_h + W_dense@W_x)^T, WhT[n][k], WdT[f][k] (bf16),
// single pass over W_h. Block 512: WdT + zero flags.
// ---------------------------------------------------------------------------
__global__ __launch_bounds__(256) void k_prep_w(
    const float* __restrict__ Wx, const float* __restrict__ Wh,
    const float* __restrict__ Wd,
    unsigned short* __restrict__ WeffT, unsigned short* __restrict__ WhT,
    unsigned short* __restrict__ WdT, unsigned int* __restrict__ flags)
{
  int tid = threadIdx.x;
  if (blockIdx.x == 512) {               // WdT; zero flags
    for (int i = 0; i < 17; ++i) flags[i * 256 + tid] = 0u;
    for (int i = 0; i < 128; ++i) {
      int idx = i * 256 + tid;
      int f = idx >> 10, k = idx & 1023;
      WdT[idx] = f2bf(Wd[k * 32 + f]);
    }
    return;
  }
  __shared__ float wx[32 * 256];              // 32 KB: W_x[f][n-tile]
  __shared__ unsigned short resE[32 * 256];   // 16 KB
  __shared__ unsigned short resH[32 * 256];   // 16 KB
  int kt = blockIdx.x & 31, nt = blockIdx.x >> 5;
  int k0 = kt * 32, n0 = nt * 256;
  for (int i = 0; i < 32; ++i) {
    int lin = i * 256 + tid;
    wx[lin] = Wx[(size_t)(lin >> 8) * NG + n0 + (lin & 255)];
  }
  __syncthreads();
  for (int kr = 0; kr < 32; ++kr) {
    int k = k0 + kr;
    float v = Wh[(size_t)k * NG + n0 + tid];
    float acc = 0.f;
#pragma unroll
    for (int f = 0; f < 32; ++f) acc += Wd[k * 32 + f] * wx[f * 256 + tid];
    resH[kr * 256 + tid] = f2bf(v);
    resE[kr * 256 + tid] = f2bf(v + acc);
  }
  __syncthreads();
#pragma unroll
  for (int pass = 0; pass < 2; ++pass) {
    const unsigned short* res = pass ? resH : resE;
    unsigned short* dst = (pass ? WhT : WeffT) + (size_t)(n0 + tid) * H_SZ + k0;
    unsigned int vals[16];
#pragma unroll
    for (int p = 0; p < 16; ++p)
      vals[p] = (unsigned int)res[(2 * p) * 256 + tid] |
                ((unsigned int)res[(2 * p + 1) * 256 + tid] << 16);
#pragma unroll
    for (int qd = 0; qd < 4; ++qd) {
      uint4 v4; v4.x = vals[4*qd]; v4.y = vals[4*qd+1]; v4.z = vals[4*qd+2]; v4.w = vals[4*qd+3];
      ((uint4*)dst)[qd] = v4;
    }
  }
}

// ---------------------------------------------------------------------------
// Persistent LSTM. 256 blocks x 256 threads, 1 block/CU (82 KB LDS).
// Group = b&7 owns 32 batch rows; its 32 blocks (slot = b>>3) each own 32
// h-cols. Barrier: per-block padded flags; RELAXED agent polls (no cache
// maintenance per iteration), then ONE acquire fence (L2 inv) per step;
// release = single release atomic store (one buffer_wbl2 + store). This is
// the round-4 kernel with the per-poll L2-invalidate / per-release RMW
// removed — correctness does NOT depend on block->XCD mapping.
// W_eff in VGPRs (64 x short8/wave), c in VGPRs, bias in acc init.
// ---------------------------------------------------------------------------
__global__ __launch_bounds__(256, 1) void k_persist(
    const unsigned short* __restrict__ WeffT,
    const unsigned short* __restrict__ WhT,
    const float* __restrict__ x0,
    const float* __restrict__ h0,
    const float* __restrict__ c0,
    const float* __restrict__ Wx,
    const float* __restrict__ bvec,
    const float* __restrict__ bd,
    const unsigned short* __restrict__ WdT,
    unsigned short* __restrict__ hbuf0,
    unsigned short* __restrict__ hbuf1,
    float* __restrict__ out,
    unsigned int* __restrict__ flags)
{
  const int b = blockIdx.x;
  const int xcd = b & 7, slot = b >> 3;    // round-robin blockIdx->XCD (perf hint only)
  const int m0 = xcd << 5;                 // 32 batch rows per group
  const int nh = slot << 5;                // 32 h-cols per block
  const int tid = threadIdx.x, lane = tid & 63, g = tid >> 6;  // wave = gate

  __shared__ unsigned short Ab[32 * 1024]; // 64 KB staged h tile (swizzled)
  __shared__ float zlds[4][32][33];        // padded gate exchange
  __shared__ float yp[8][32];              // y partial sums

  // --- init: h0 slice -> bf16, c0 -> registers ---
  float creg[4];
#pragma unroll
  for (int e = 0; e < 4; ++e) {
    int idx = e * 256 + tid;
    int m = idx >> 5, cc = idx & 31;
    size_t gi = (size_t)(m0 + m) * H_SZ + nh + cc;
    hbuf0[gi] = f2bf(h0[gi]);
    creg[e] = c0[gi];
  }
  __syncthreads();                         // per-wave vmcnt drained to L2
  unsigned int* myflag = flags + (((xcd << 5) | slot) << 4);  // 64B stride
  if (tid == 0)
    __hip_atomic_store(myflag, 1u, __ATOMIC_RELEASE, __HIP_MEMORY_SCOPE_AGENT);

  // --- per-lane bias: bfv[nf] (steady-state), u0r[mf][nf][e] (step 0) ---
  const int col = lane & 15;
  const int kq = lane >> 4;
  const int n0a0 = (g << 10) + nh + col;
  const int n0a1 = n0a0 + 16;
  float bfv0 = bvec[n0a0], bfv1 = bvec[n0a1];
  float u0r[2][2][4];
#pragma unroll
  for (int mf = 0; mf < 2; ++mf)
#pragma unroll
    for (int e = 0; e < 4; ++e) { u0r[mf][0][e] = bfv0; u0r[mf][1][e] = bfv1; }
  for (int f = 0; f < 32; ++f) {
    float wx0 = Wx[(size_t)f * NG + n0a0];
    float wx1 = Wx[(size_t)f * NG + n0a1];
    bfv0 += bd[f] * wx0; bfv1 += bd[f] * wx1;
#pragma unroll
    for (int mf = 0; mf < 2; ++mf)
#pragma unroll
      for (int e = 0; e < 4; ++e) {
        float xv = x0[(m0 + mf * 16 + (kq << 2) + e) * 32 + f];
        u0r[mf][0][e] += xv * wx0;
        u0r[mf][1][e] += xv * wx1;
      }
  }

  // --- W fragments in registers: wr[nf][kk] ---
  short8 wr[2][32];
  {
    const unsigned short* p0 = WhT + (size_t)n0a0 * H_SZ + (kq << 3);
    const unsigned short* p1 = WhT + (size_t)n0a1 * H_SZ + (kq << 3);
#pragma unroll
    for (int kk = 0; kk < 32; ++kk) {
      wr[0][kk] = *(const short8*)(p0 + kk * 32);
      wr[1][kk] = *(const short8*)(p1 + kk * 32);
    }
  }

  // staging addrs (pre-swizzled source -> linear LDS dest)
  const int srow = (tid & 127) >> 2;
  const int skg  = (tid & 3) ^ ((srow >> 1) & 3);
  const int sgbase = srow * H_SZ + ((tid >> 7) << 5) + (skg << 3);
  const int wdst = (tid >> 6) << 9;        // wave-uniform ushort base
  // A-frag read offset within a chunk (1024 ushorts = 32 rows x 32 k)
  const int q = kq ^ ((col >> 1) & 3);
  const int aoff = col * 32 + (q << 3);
  // y-dot per-thread constants
  const int yf = tid & 31, ykc = tid >> 5;
  const int ysw = (slot >> 1) & 3;
  const unsigned short* wdp = WdT + (size_t)yf * H_SZ + ykc * 128;

  for (int j = 0; j <= T_SZ; ++j) {
    // group barrier: RELAXED polls, then one acquire fence (L2 inv)
    {
      const unsigned int tgt = (unsigned)(j + 1);
      if (g == 0 && lane < 32) {
        const unsigned int* fp = flags + (((xcd << 5) | lane) << 4);
        while (__hip_atomic_load(fp, __ATOMIC_RELAXED, __HIP_MEMORY_SCOPE_AGENT) < tgt)
          __builtin_amdgcn_s_sleep(2);
      }
      __syncthreads();
      __builtin_amdgcn_fence(__ATOMIC_ACQUIRE, "agent");
    }
    const unsigned short* hp = (j & 1) ? hbuf1 : hbuf0;
    unsigned short* hn = (j & 1) ? hbuf0 : hbuf1;

    // stage h tile: 64 KB, 16 x global_load_lds(16B) per thread
    {
      const unsigned short* src = hp + (size_t)m0 * H_SZ + sgbase;
#pragma unroll
      for (int it = 0; it < 16; ++it)
        stage16(src + it * 64, &Ab[it * 2048 + wdst]);
      __syncthreads();
    }

    // y partials: y_{j-1}[m0+slot][yf], this thread's 128-k slice
    if (j >= 1) {
      float acc = 0.f;
#pragma unroll
      for (int c2 = 0; c2 < 4; ++c2)
#pragma unroll
        for (int p = 0; p < 4; ++p) {
          uint4 av = *(const uint4*)(Ab + (ykc * 4 + c2) * 1024 + slot * 32 + p * 8);
          uint4 wv = *(const uint4*)(wdp + c2 * 32 + ((p ^ ysw) << 3));
          acc += __uint_as_float(av.x << 16) * __uint_as_float(wv.x << 16);
          acc += __uint_as_float(av.x & 0xffff0000u) * __uint_as_float(wv.x & 0xffff0000u);
          acc += __uint_as_float(av.y << 16) * __uint_as_float(wv.y << 16);
          acc += __uint_as_float(av.y & 0xffff0000u) * __uint_as_float(wv.y & 0xffff0000u);
          acc += __uint_as_float(av.z << 16) * __uint_as_float(wv.z << 16);
          acc += __uint_as_float(av.z & 0xffff0000u) * __uint_as_float(wv.z & 0xffff0000u);
          acc += __uint_as_float(av.w << 16) * __uint_as_float(wv.w << 16);
          acc += __uint_as_float(av.w & 0xffff0000u) * __uint_as_float(wv.w & 0xffff0000u);
        }
      yp[ykc][yf] = acc;
    }

    if (j < T_SZ) {
      // GEMM: acc = bias; += A(32x1024) @ W(1024x32) per wave (gate g)
      f32x4 acc[2][2];
#pragma unroll
      for (int mf = 0; mf < 2; ++mf)
#pragma unroll
        for (int e = 0; e < 4; ++e) {
          acc[mf][0][e] = (j == 0) ? u0r[mf][0][e] : bfv0;
          acc[mf][1][e] = (j == 0) ? u0r[mf][1][e] : bfv1;
        }
#pragma unroll
      for (int kk = 0; kk < 32; ++kk) {
        short8 a0 = *(const short8*)(Ab + kk * 1024 + aoff);
        short8 a1 = *(const short8*)(Ab + kk * 1024 + 512 + aoff);
        acc[0][0] = __builtin_amdgcn_mfma_f32_16x16x32_bf16(a0, wr[0][kk], acc[0][0], 0, 0, 0);
        acc[1][0] = __builtin_amdgcn_mfma_f32_16x16x32_bf16(a1, wr[0][kk], acc[1][0], 0, 0, 0);
        acc[0][1] = __builtin_amdgcn_mfma_f32_16x16x32_bf16(a0, wr[1][kk], acc[0][1], 0, 0, 0);
        acc[1][1] = __builtin_amdgcn_mfma_f32_16x16x32_bf16(a1, wr[1][kk], acc[1][1], 0, 0, 0);
      }
      if (j == 0) {                        // switch to folded weights
        const unsigned short* p0 = WeffT + (size_t)n0a0 * H_SZ + (kq << 3);
        const unsigned short* p1 = WeffT + (size_t)n0a1 * H_SZ + (kq << 3);
#pragma unroll
        for (int kk = 0; kk < 32; ++kk) {
          wr[0][kk] = *(const short8*)(p0 + kk * 32);
          wr[1][kk] = *(const short8*)(p1 + kk * 32);
        }
      }
      // z exchange: D layout col=lane&15, row=(lane>>4)*4+e
#pragma unroll
      for (int mf = 0; mf < 2; ++mf)
#pragma unroll
        for (int nf = 0; nf < 2; ++nf)
#pragma unroll
          for (int e = 0; e < 4; ++e)
            zlds[g][mf * 16 + (kq << 2) + e][nf * 16 + col] = acc[mf][nf][e];
    }
    __syncthreads();                       // zlds + yp ready

    if (j < T_SZ) {
      // cell update: 1024 cells, 4/thread, c in registers
#pragma unroll
      for (int e = 0; e < 4; ++e) {
        int idx = e * 256 + tid;
        int m = idx >> 5, cc = idx & 31;
        float zi = zlds[0][m][cc];
        float zf = zlds[1][m][cc];
        float zg = zlds[2][m][cc];
        float zo = zlds[3][m][cc];
        float iv = sigf(zi), fv = sigf(zf), gv = tanh_fast(zg), ov = sigf(zo);
        float cn = fv * creg[e] + iv * gv;
        creg[e] = cn;
        hn[(size_t)(m0 + m) * H_SZ + nh + cc] = f2bf(ov * tanh_fast(cn));
      }
    }
    if (j >= 1 && tid < 32) {              // finish y_{j-1}: one 128B row
      float s = bd[tid];
#pragma unroll
      for (int kc = 0; kc < 8; ++kc) s += yp[kc][tid];
      out[(size_t)(m0 + slot) * (T_SZ * F_SZ) + (size_t)(j - 1) * F_SZ + tid] = s;
    }
    __syncthreads();                       // all waves' stores drained (pre-barrier vmcnt)
    if (tid == 0 && j < T_SZ)
      __hip_atomic_store(myflag, (unsigned)(j + 2), __ATOMIC_RELEASE,
                         __HIP_MEMORY_SCOPE_AGENT);
  }
}

// ---------------------------------------------------------------------------
extern "C" void kernel_launch(void* const* d_in, const int* in_sizes, int n_in,
                              void* d_out, int out_size, void* d_ws, size_t ws_size,
                              hipStream_t stream)
{
  const float* x0 = (const float*)d_in[0];   // (256,1,32)
  const float* h0 = (const float*)d_in[1];   // (256,1024)
  const float* c0 = (const float*)d_in[2];
  // d_in[3] targets unused
  const float* Wx = (const float*)d_in[4];   // (32,4096)
  const float* Wh = (const float*)d_in[5];   // (1024,4096)
  const float* bv = (const float*)d_in[6];   // (4096)
  const float* Wd = (const float*)d_in[7];   // (1024,32)
  const float* bd = (const float*)d_in[8];   // (32)
  float* out = (float*)d_out;                // (256,96,32) fp32

  char* p = (char*)d_ws;
  unsigned short* WeffT = (unsigned short*)p; p += (size_t)NG * H_SZ * 2;   // 8 MB
  unsigned short* WhT   = (unsigned short*)p; p += (size_t)NG * H_SZ * 2;   // 8 MB
  unsigned short* WdT   = (unsigned short*)p; p += (size_t)F_SZ * H_SZ * 2; // 64 KB
  unsigned short* hb0   = (unsigned short*)p; p += (size_t)B_SZ * H_SZ * 2; // 512 KB
  unsigned short* hb1   = (unsigned short*)p; p += (size_t)B_SZ * H_SZ * 2; // 512 KB
  unsigned int* flags   = (unsigned int*)p;  p += 4352 * 4;                 // 17 KB
  (void)ws_size; (void)in_sizes; (void)n_in; (void)out_size;

  k_prep_w<<<dim3(513), dim3(256), 0, stream>>>(Wx, Wh, Wd, WeffT, WhT, WdT, flags);

  k_persist<<<dim3(256), dim3(256), 0, stream>>>(
      WeffT, WhT, x0, h0, c0, Wx, bv, bd, WdT, hb0, hb1, out, flags);
}

// Round 7
// 755.059 us; speedup vs baseline: 2.2872x; 2.2872x over previous
//
#include <hip/hip_runtime.h>
#include <hip/hip_bf16.h>
#include <stdint.h>

#define B_SZ 256
#define H_SZ 1024
#define NG   4096   // 4*H
#define F_SZ 32
#define T_SZ 96

typedef __attribute__((ext_vector_type(8))) short short8;
typedef __attribute__((ext_vector_type(4))) float f32x4;

__device__ __forceinline__ unsigned short f2bf(float x) {
  unsigned int u = __float_as_uint(x);
  u += 0x7fffu + ((u >> 16) & 1u);   // RNE
  return (unsigned short)(u >> 16);
}
__device__ __forceinline__ float sigf(float x) {
  return 1.f / (1.f + __expf(-x));
}
__device__ __forceinline__ float tanh_fast(float x) {
  float e = __expf(-2.f * fabsf(x));
  float t = (1.f - e) / (1.f + e);
  return copysignf(t, x);
}
__device__ __forceinline__ void stage16(const void* g, void* l) {
  __builtin_amdgcn_global_load_lds(
      (const __attribute__((address_space(1))) void*)g,
      (__attribute__((address_space(3))) void*)l, 16, 0, 0);
}

// ---------------------------------------------------------------------------
// Prep: WeffT[n][k] = (W_h + W_dense@W_x)^T, WhT[n][k], WdT[f][k] (bf16),
// single pass over W_h. Block 512: WdT + zero flags/xcctab.
// ---------------------------------------------------------------------------
__global__ __launch_bounds__(256) void k_prep_w(
    const float* __restrict__ Wx, const float* __restrict__ Wh,
    const float* __restrict__ Wd,
    unsigned short* __restrict__ WeffT, unsigned short* __restrict__ WhT,
    unsigned short* __restrict__ WdT, unsigned int* __restrict__ flags)
{
  int tid = threadIdx.x;
  if (blockIdx.x == 512) {               // WdT; zero flags (4096) + xcctab (256)
    for (int i = 0; i < 17; ++i) flags[i * 256 + tid] = 0u;
    for (int i = 0; i < 128; ++i) {
      int idx = i * 256 + tid;
      int f = idx >> 10, k = idx & 1023;
      WdT[idx] = f2bf(Wd[k * 32 + f]);
    }
    return;
  }
  __shared__ float wx[32 * 256];              // 32 KB: W_x[f][n-tile]
  __shared__ unsigned short resE[32 * 256];   // 16 KB
  __shared__ unsigned short resH[32 * 256];   // 16 KB
  int kt = blockIdx.x & 31, nt = blockIdx.x >> 5;
  int k0 = kt * 32, n0 = nt * 256;
  for (int i = 0; i < 32; ++i) {
    int lin = i * 256 + tid;
    wx[lin] = Wx[(size_t)(lin >> 8) * NG + n0 + (lin & 255)];
  }
  __syncthreads();
  for (int kr = 0; kr < 32; ++kr) {
    int k = k0 + kr;
    float v = Wh[(size_t)k * NG + n0 + tid];
    float acc = 0.f;
#pragma unroll
    for (int f = 0; f < 32; ++f) acc += Wd[k * 32 + f] * wx[f * 256 + tid];
    resH[kr * 256 + tid] = f2bf(v);
    resE[kr * 256 + tid] = f2bf(v + acc);
  }
  __syncthreads();
#pragma unroll
  for (int pass = 0; pass < 2; ++pass) {
    const unsigned short* res = pass ? resH : resE;
    unsigned short* dst = (pass ? WhT : WeffT) + (size_t)(n0 + tid) * H_SZ + k0;
    unsigned int vals[16];
#pragma unroll
    for (int p = 0; p < 16; ++p)
      vals[p] = (unsigned int)res[(2 * p) * 256 + tid] |
                ((unsigned int)res[(2 * p + 1) * 256 + tid] << 16);
#pragma unroll
    for (int qd = 0; qd < 4; ++qd) {
      uint4 v4; v4.x = vals[4*qd]; v4.y = vals[4*qd+1]; v4.z = vals[4*qd+2]; v4.w = vals[4*qd+3];
      ((uint4*)dst)[qd] = v4;
    }
  }
}

// ---------------------------------------------------------------------------
// Persistent LSTM. 256 blocks x 256 threads, 1 block/CU (82 KB LDS).
// Group = b&7 owns 32 batch rows; its 32 blocks (slot=b>>3) each own 32
// h-cols. Coherence protocol is RUNTIME-SELECTED per group:
//  - step-0 barrier is agent-fenced (one wbl2+inv, one time) and also
//    publishes each block's hardware XCC_ID; each group checks all 32
//    members share one XCD.
//  - PURE group (expected under round-robin dispatch): h stays in the shared
//    XCD L2. Release = __syncthreads (per-wave vmcnt drain -> h in L2) +
//    RELAXED agent flag store (no wbl2). Acquire = RELAXED agent polls +
//    buffer_inv sc0 (L1-only, CU-local). Zero L2 maintenance per step --
//    rounds 4/6 showed each agent fence's full-L2 scan costs ~5-8us/step.
//  - IMPURE group: falls back to round-6 agent-fenced protocol (correct for
//    any mapping).
// W_eff in VGPRs (64 x short8/wave), c in VGPRs, bias in acc init.
// ---------------------------------------------------------------------------
__global__ __launch_bounds__(256, 1) void k_persist(
    const unsigned short* __restrict__ WeffT,
    const unsigned short* __restrict__ WhT,
    const float* __restrict__ x0,
    const float* __restrict__ h0,
    const float* __restrict__ c0,
    const float* __restrict__ Wx,
    const float* __restrict__ bvec,
    const float* __restrict__ bd,
    const unsigned short* __restrict__ WdT,
    unsigned short* __restrict__ hbuf0,
    unsigned short* __restrict__ hbuf1,
    float* __restrict__ out,
    unsigned int* __restrict__ flags)
{
  const int b = blockIdx.x;
  const int xcd = b & 7, slot = b >> 3;    // data-layout grouping (fixed)
  const int m0 = xcd << 5;                 // 32 batch rows per group
  const int nh = slot << 5;                // 32 h-cols per block
  const int tid = threadIdx.x, lane = tid & 63, g = tid >> 6;  // wave = gate

  __shared__ unsigned short Ab[32 * 1024]; // 64 KB staged h tile (swizzled)
  __shared__ float zlds[4][32][33];        // padded gate exchange
  __shared__ float yp[8][32];              // y partial sums
  __shared__ unsigned int sPure;

  unsigned int* xcctab = flags + 4096;
  unsigned int myxcc;
  asm volatile("s_getreg_b32 %0, hwreg(HW_REG_XCC_ID)" : "=s"(myxcc));
  myxcc &= 15u;

  // --- init: h0 slice -> bf16, c0 -> registers ---
  float creg[4];
#pragma unroll
  for (int e = 0; e < 4; ++e) {
    int idx = e * 256 + tid;
    int m = idx >> 5, cc = idx & 31;
    size_t gi = (size_t)(m0 + m) * H_SZ + nh + cc;
    hbuf0[gi] = f2bf(h0[gi]);
    creg[e] = c0[gi];
  }
  __syncthreads();                         // per-wave vmcnt drained -> L2
  unsigned int* myflag = flags + (((xcd << 5) | slot) << 4);  // 64B stride
  if (tid == 0) {
    __hip_atomic_store(&xcctab[b], myxcc, __ATOMIC_RELAXED,
                       __HIP_MEMORY_SCOPE_AGENT);
    __hip_atomic_store(myflag, 1u, __ATOMIC_RELEASE,
                       __HIP_MEMORY_SCOPE_AGENT);      // one-time wbl2
  }

  // --- per-lane bias: bfv[nf] (steady-state), u0r[mf][nf][e] (step 0) ---
  const int col = lane & 15;
  const int kq = lane >> 4;
  const int n0a0 = (g << 10) + nh + col;
  const int n0a1 = n0a0 + 16;
  float bfv0 = bvec[n0a0], bfv1 = bvec[n0a1];
  float u0r[2][2][4];
#pragma unroll
  for (int mf = 0; mf < 2; ++mf)
#pragma unroll
    for (int e = 0; e < 4; ++e) { u0r[mf][0][e] = bfv0; u0r[mf][1][e] = bfv1; }
  for (int f = 0; f < 32; ++f) {
    float wx0 = Wx[(size_t)f * NG + n0a0];
    float wx1 = Wx[(size_t)f * NG + n0a1];
    bfv0 += bd[f] * wx0; bfv1 += bd[f] * wx1;
#pragma unroll
    for (int mf = 0; mf < 2; ++mf)
#pragma unroll
      for (int e = 0; e < 4; ++e) {
        float xv = x0[(m0 + mf * 16 + (kq << 2) + e) * 32 + f];
        u0r[mf][0][e] += xv * wx0;
        u0r[mf][1][e] += xv * wx1;
      }
  }

  // --- W fragments in registers: wr[nf][kk] ---
  short8 wr[2][32];
  {
    const unsigned short* p0 = WhT + (size_t)n0a0 * H_SZ + (kq << 3);
    const unsigned short* p1 = WhT + (size_t)n0a1 * H_SZ + (kq << 3);
#pragma unroll
    for (int kk = 0; kk < 32; ++kk) {
      wr[0][kk] = *(const short8*)(p0 + kk * 32);
      wr[1][kk] = *(const short8*)(p1 + kk * 32);
    }
  }

  // staging addrs (pre-swizzled source -> linear LDS dest)
  const int srow = (tid & 127) >> 2;
  const int skg  = (tid & 3) ^ ((srow >> 1) & 3);
  const int sgbase = srow * H_SZ + ((tid >> 7) << 5) + (skg << 3);
  const int wdst = (tid >> 6) << 9;        // wave-uniform ushort base
  // A-frag read offset within a chunk (1024 ushorts = 32 rows x 32 k)
  const int q = kq ^ ((col >> 1) & 3);
  const int aoff = col * 32 + (q << 3);
  // y-dot per-thread constants
  const int yf = tid & 31, ykc = tid >> 5;
  const int ysw = (slot >> 1) & 3;
  const unsigned short* wdp = WdT + (size_t)yf * H_SZ + ykc * 128;

  bool pure = false;
  for (int j = 0; j <= T_SZ; ++j) {
    // group barrier: RELAXED agent polls (same-scope pair with the release)
    {
      const unsigned int tgt = (unsigned)(j + 1);
      if (g == 0 && lane < 32) {
        const unsigned int* fp = flags + (((xcd << 5) | lane) << 4);
        while (__hip_atomic_load(fp, __ATOMIC_RELAXED, __HIP_MEMORY_SCOPE_AGENT) < tgt)
          __builtin_amdgcn_s_sleep(1);
      }
      __syncthreads();
    }
    if (j == 0) {
      __builtin_amdgcn_fence(__ATOMIC_ACQUIRE, "agent");  // one-time L2 inv
      bool eq = true;
      if (g == 0 && lane < 32)
        eq = (__hip_atomic_load(&xcctab[(lane << 3) | xcd], __ATOMIC_RELAXED,
                                __HIP_MEMORY_SCOPE_AGENT) == myxcc);
      unsigned long long bal = __ballot(eq);
      if (tid == 0) sPure = (bal == ~0ull) ? 1u : 0u;
      __syncthreads();
      pure = (sPure != 0u);
    } else if (pure) {
      asm volatile("buffer_inv sc0" ::: "memory");        // L1-only inv
    } else {
      __builtin_amdgcn_fence(__ATOMIC_ACQUIRE, "agent");  // fallback: L2 inv
    }
    const unsigned short* hp = (j & 1) ? hbuf1 : hbuf0;
    unsigned short* hn = (j & 1) ? hbuf0 : hbuf1;

    // stage h tile: 64 KB, 16 x global_load_lds(16B) per thread
    {
      const unsigned short* src = hp + (size_t)m0 * H_SZ + sgbase;
#pragma unroll
      for (int it = 0; it < 16; ++it)
        stage16(src + it * 64, &Ab[it * 2048 + wdst]);
      __syncthreads();
    }

    // y partials: y_{j-1}[m0+slot][yf], this thread's 128-k slice
    if (j >= 1) {
      float acc = 0.f;
#pragma unroll
      for (int c2 = 0; c2 < 4; ++c2)
#pragma unroll
        for (int p = 0; p < 4; ++p) {
          uint4 av = *(const uint4*)(Ab + (ykc * 4 + c2) * 1024 + slot * 32 + p * 8);
          uint4 wv = *(const uint4*)(wdp + c2 * 32 + ((p ^ ysw) << 3));
          acc += __uint_as_float(av.x << 16) * __uint_as_float(wv.x << 16);
          acc += __uint_as_float(av.x & 0xffff0000u) * __uint_as_float(wv.x & 0xffff0000u);
          acc += __uint_as_float(av.y << 16) * __uint_as_float(wv.y << 16);
          acc += __uint_as_float(av.y & 0xffff0000u) * __uint_as_float(wv.y & 0xffff0000u);
          acc += __uint_as_float(av.z << 16) * __uint_as_float(wv.z << 16);
          acc += __uint_as_float(av.z & 0xffff0000u) * __uint_as_float(wv.z & 0xffff0000u);
          acc += __uint_as_float(av.w << 16) * __uint_as_float(wv.w << 16);
          acc += __uint_as_float(av.w & 0xffff0000u) * __uint_as_float(wv.w & 0xffff0000u);
        }
      yp[ykc][yf] = acc;
    }

    if (j < T_SZ) {
      // GEMM: acc = bias; += A(32x1024) @ W(1024x32) per wave (gate g)
      f32x4 acc[2][2];
#pragma unroll
      for (int mf = 0; mf < 2; ++mf)
#pragma unroll
        for (int e = 0; e < 4; ++e) {
          acc[mf][0][e] = (j == 0) ? u0r[mf][0][e] : bfv0;
          acc[mf][1][e] = (j == 0) ? u0r[mf][1][e] : bfv1;
        }
#pragma unroll
      for (int kk = 0; kk < 32; ++kk) {
        short8 a0 = *(const short8*)(Ab + kk * 1024 + aoff);
        short8 a1 = *(const short8*)(Ab + kk * 1024 + 512 + aoff);
        acc[0][0] = __builtin_amdgcn_mfma_f32_16x16x32_bf16(a0, wr[0][kk], acc[0][0], 0, 0, 0);
        acc[1][0] = __builtin_amdgcn_mfma_f32_16x16x32_bf16(a1, wr[0][kk], acc[1][0], 0, 0, 0);
        acc[0][1] = __builtin_amdgcn_mfma_f32_16x16x32_bf16(a0, wr[1][kk], acc[0][1], 0, 0, 0);
        acc[1][1] = __builtin_amdgcn_mfma_f32_16x16x32_bf16(a1, wr[1][kk], acc[1][1], 0, 0, 0);
      }
      if (j == 0) {                        // switch to folded weights
        const unsigned short* p0 = WeffT + (size_t)n0a0 * H_SZ + (kq << 3);
        const unsigned short* p1 = WeffT + (size_t)n0a1 * H_SZ + (kq << 3);
#pragma unroll
        for (int kk = 0; kk < 32; ++kk) {
          wr[0][kk] = *(const short8*)(p0 + kk * 32);
          wr[1][kk] = *(const short8*)(p1 + kk * 32);
        }
      }
      // z exchange: D layout col=lane&15, row=(lane>>4)*4+e
#pragma unroll
      for (int mf = 0; mf < 2; ++mf)
#pragma unroll
        for (int nf = 0; nf < 2; ++nf)
#pragma unroll
          for (int e = 0; e < 4; ++e)
            zlds[g][mf * 16 + (kq << 2) + e][nf * 16 + col] = acc[mf][nf][e];
    }
    __syncthreads();                       // zlds + yp ready

    if (j < T_SZ) {
      // cell update: 1024 cells, 4/thread, c in registers
#pragma unroll
      for (int e = 0; e < 4; ++e) {
        int idx = e * 256 + tid;
        int m = idx >> 5, cc = idx & 31;
        float zi = zlds[0][m][cc];
        float zf = zlds[1][m][cc];
        float zg = zlds[2][m][cc];
        float zo = zlds[3][m][cc];
        float iv = sigf(zi), fv = sigf(zf), gv = tanh_fast(zg), ov = sigf(zo);
        float cn = fv * creg[e] + iv * gv;
        creg[e] = cn;
        hn[(size_t)(m0 + m) * H_SZ + nh + cc] = f2bf(ov * tanh_fast(cn));
      }
    }
    if (j >= 1 && tid < 32) {              // finish y_{j-1}: one 128B row
      float s = bd[tid];
#pragma unroll
      for (int kc = 0; kc < 8; ++kc) s += yp[kc][tid];
      out[(size_t)(m0 + slot) * (T_SZ * F_SZ) + (size_t)(j - 1) * F_SZ + tid] = s;
    }
    __syncthreads();                       // all waves' h stores drained -> L2
    if (tid == 0 && j < T_SZ) {
      if (pure)
        __hip_atomic_store(myflag, (unsigned)(j + 2), __ATOMIC_RELAXED,
                           __HIP_MEMORY_SCOPE_AGENT);   // no wbl2
      else
        __hip_atomic_store(myflag, (unsigned)(j + 2), __ATOMIC_RELEASE,
                           __HIP_MEMORY_SCOPE_AGENT);
    }
  }
}

// ---------------------------------------------------------------------------
extern "C" void kernel_launch(void* const* d_in, const int* in_sizes, int n_in,
                              void* d_out, int out_size, void* d_ws, size_t ws_size,
                              hipStream_t stream)
{
  const float* x0 = (const float*)d_in[0];   // (256,1,32)
  const float* h0 = (const float*)d_in[1];   // (256,1024)
  const float* c0 = (const float*)d_in[2];
  // d_in[3] targets unused
  const float* Wx = (const float*)d_in[4];   // (32,4096)
  const float* Wh = (const float*)d_in[5];   // (1024,4096)
  const float* bv = (const float*)d_in[6];   // (4096)
  const float* Wd = (const float*)d_in[7];   // (1024,32)
  const float* bd = (const float*)d_in[8];   // (32)
  float* out = (float*)d_out;                // (256,96,32) fp32

  char* p = (char*)d_ws;
  unsigned short* WeffT = (unsigned short*)p; p += (size_t)NG * H_SZ * 2;   // 8 MB
  unsigned short* WhT   = (unsigned short*)p; p += (size_t)NG * H_SZ * 2;   // 8 MB
  unsigned short* WdT   = (unsigned short*)p; p += (size_t)F_SZ * H_SZ * 2; // 64 KB
  unsigned short* hb0   = (unsigned short*)p; p += (size_t)B_SZ * H_SZ * 2; // 512 KB
  unsigned short* hb1   = (unsigned short*)p; p += (size_t)B_SZ * H_SZ * 2; // 512 KB
  unsigned int* flags   = (unsigned int*)p;  p += 4352 * 4;  // flags + xcctab
  (void)ws_size; (void)in_sizes; (void)n_in; (void)out_size;

  k_prep_w<<<dim3(513), dim3(256), 0, stream>>>(Wx, Wh, Wd, WeffT, WhT, WdT, flags);

  k_persist<<<dim3(256), dim3(256), 0, stream>>>(
      WeffT, WhT, x0, h0, c0, Wx, bv, bd, WdT, hb0, hb1, out, flags);
}